// Round 5
// baseline (353.907 us; speedup 1.0000x reference)
//
#include <hip/hip_runtime.h>

// Problem constants (fixed by the reference):
//   B=4, C=64, NX=512, NY=512, N = 120000 pillars (~11% cell density)
#define NXC 512
#define NYC 512
#define CC  64
#define BC  4

typedef float v4f __attribute__((ext_vector_type(4)));

// ---------------------------------------------------------------------------
// Kernel 1: zero the pillar-index map (4 MB). d_ws is poisoned 0xAA before
// every timed launch, so this must run each call.
__global__ void pp_zero_map(int4* __restrict__ map4, int n4) {
    int i = blockIdx.x * blockDim.x + threadIdx.x;
    if (i < n4) map4[i] = make_int4(0, 0, 0, 0);
}

// ---------------------------------------------------------------------------
// Kernel 2: scatter pillar index n+1 into map[b*NX*NY + x*NY + y].
// coords are unique per (b,x,y) so no write races.
__global__ void pp_build_map(const int* __restrict__ coords, int* __restrict__ map, int N) {
    int n = blockIdx.x * blockDim.x + threadIdx.x;
    if (n >= N) return;
    int4 c = *(const int4*)(coords + 4 * (size_t)n);  // (b, z, y, x)
    map[((size_t)c.x * NXC + c.w) * NYC + c.z] = n + 1;
}

// ---------------------------------------------------------------------------
// Kernel 3: gather, write-locality-first layout. One block per
// (b, c, x-chunk-of-64): each block writes a 128 KB FULLY CONTIGUOUS output
// segment (sequential NT store stream, fill-like DRAM page locality).
// Reads: 128 KB map slice, coalesced int4 (L2-resident: 4 MB map is cached
// per-XCD; 64x c-reuse served at L2 BW). vf loads are exec-masked scalars —
// only ~11% of lanes are on a non-empty cell, so the scatter is cheap and
// L2/L3-served after first touch.
__global__ void __launch_bounds__(256) pp_gather(const float* __restrict__ vf,
                                                 const int* __restrict__ map,
                                                 float* __restrict__ out) {
    int bid = blockIdx.x;                 // 0 .. 2047
    int b   = bid >> 9;                   // /512 -> batch
    int c   = (bid >> 3) & 63;            // channel
    int x0  = (bid & 7) << 6;             // x-chunk base: 0,64,...,448
    int t   = threadIdx.x;                // 0 .. 255

    const int* mbase = map + ((size_t)(b * NXC + x0) << 9);            // 128 KB slice
    float* obase = out + ((size_t)(b * CC + c) * NXC + x0) * NYC;      // 128 KB segment

    #pragma unroll 4
    for (int i = 0; i < 32; ++i) {
        int lin = i * 256 + t;            // 0..8191: (x_local*128 + y_group)
        int4 m = *(const int4*)(mbase + 4 * (size_t)lin);
        v4f v;
        v.x = m.x ? vf[(size_t)(m.x - 1) * CC + c] : 0.0f;
        v.y = m.y ? vf[(size_t)(m.y - 1) * CC + c] : 0.0f;
        v.z = m.z ? vf[(size_t)(m.z - 1) * CC + c] : 0.0f;
        v.w = m.w ? vf[(size_t)(m.w - 1) * CC + c] : 0.0f;
        __builtin_nontemporal_store(v, (v4f*)(obase + 4 * (size_t)lin));
    }
}

extern "C" void kernel_launch(void* const* d_in, const int* in_sizes, int n_in,
                              void* d_out, int out_size, void* d_ws, size_t ws_size,
                              hipStream_t stream) {
    const float* vf     = (const float*)d_in[0];
    const int*   coords = (const int*)d_in[1];
    // d_in[2] = batch_size scalar (fixed at 4; dims are compile-time constants)

    float* out = (float*)d_out;
    int*   map = (int*)d_ws;                       // 4 MB: B*NX*NY int32

    const int N = in_sizes[0] / CC;                // 120000 pillars
    const int MAPN  = BC * NXC * NYC;              // 1,048,576
    const int MAPN4 = MAPN / 4;                    // 262,144 int4s

    pp_zero_map<<<(MAPN4 + 255) / 256, 256, 0, stream>>>((int4*)map, MAPN4);
    pp_build_map<<<(N + 255) / 256, 256, 0, stream>>>(coords, map, N);
    pp_gather<<<BC * CC * 8, 256, 0, stream>>>(vf, map, out);
}

// Round 6
// 298.250 us; speedup vs baseline: 1.1866x; 1.1866x over previous
//
#include <hip/hip_runtime.h>

// Problem constants (fixed by the reference):
//   B=4, C=64, NX=512, NY=512, N = 120000 pillars (~11% cell density)
#define NXC 512
#define NYC 512
#define CC  64
#define BC  4
#define PLANE (NXC * NYC)   // 262144 floats per (b,c) plane

typedef float v4f __attribute__((ext_vector_type(4)));

// ---------------------------------------------------------------------------
// Kernel 1: scatter pillar index n+1 into map[b*NX*NY + x*NY + y].
// (map + zero-row are zeroed by hipMemsetAsync in kernel_launch.)
// coords are unique per (b,x,y) so no write races.
__global__ void pp_build_map(const int* __restrict__ coords, int* __restrict__ map, int N) {
    int n = blockIdx.x * blockDim.x + threadIdx.x;
    if (n >= N) return;
    int4 c = *(const int4*)(coords + 4 * (size_t)n);  // (b, z, y, x)
    map[((size_t)c.x * NXC + c.w) * NYC + c.z] = n + 1;
}

// ---------------------------------------------------------------------------
// Kernel 2: gather (R3 structure, REGULAR stores — NT A/B test).
// One block per (b, x) output row; 256 threads. Thread t owns 4 consecutive
// y's (y4 = (t&127)*4) and a 32-wide c-half (c0 = (t>>7)*32). Reads its 4
// pillar rows as float4s, transposes 4x4 in registers, writes 4 coalesced
// float4s per group into the c-planes (1 KB contiguous per wave store).
// Empty pillars read a shared 256 B zero-row (L1-resident) -> branchless.
__global__ void __launch_bounds__(256) pp_gather(const float* __restrict__ vf,
                                                 const int* __restrict__ map,
                                                 const float* __restrict__ zrow,
                                                 float* __restrict__ out) {
    int bx = blockIdx.x;            // 0 .. B*NX-1
    int t  = threadIdx.x;           // 0 .. 255
    int b  = bx >> 9;               // /512
    int x  = bx & (NXC - 1);

    int c0 = (t >> 7) << 5;         // 0 or 32
    int y4 = (t & 127) << 2;        // 0,4,...,508

    int4 nn = *(const int4*)(map + (size_t)bx * NYC + y4);

    const float* p0 = nn.x ? vf + (size_t)(nn.x - 1) * CC : zrow;
    const float* p1 = nn.y ? vf + (size_t)(nn.y - 1) * CC : zrow;
    const float* p2 = nn.z ? vf + (size_t)(nn.z - 1) * CC : zrow;
    const float* p3 = nn.w ? vf + (size_t)(nn.w - 1) * CC : zrow;

    float* ob = out + ((size_t)(b * CC + c0) * NXC + x) * NYC + y4;

    #pragma unroll
    for (int cg = 0; cg < 8; ++cg) {
        int c = c0 + cg * 4;
        v4f va = *(const v4f*)(p0 + c);   // pillar @ y4+0, channels c..c+3
        v4f vb = *(const v4f*)(p1 + c);   // pillar @ y4+1
        v4f vc = *(const v4f*)(p2 + c);   // pillar @ y4+2
        v4f vd = *(const v4f*)(p3 + c);   // pillar @ y4+3
        float* o = ob + (size_t)cg * 4 * PLANE;
        *(v4f*)(o)                       = (v4f){va.x, vb.x, vc.x, vd.x};  // plane c
        *(v4f*)(o + PLANE)               = (v4f){va.y, vb.y, vc.y, vd.y};  // plane c+1
        *(v4f*)(o + 2 * (size_t)PLANE)   = (v4f){va.z, vb.z, vc.z, vd.z};  // plane c+2
        *(v4f*)(o + 3 * (size_t)PLANE)   = (v4f){va.w, vb.w, vc.w, vd.w};  // plane c+3
    }
}

extern "C" void kernel_launch(void* const* d_in, const int* in_sizes, int n_in,
                              void* d_out, int out_size, void* d_ws, size_t ws_size,
                              hipStream_t stream) {
    const float* vf     = (const float*)d_in[0];
    const int*   coords = (const int*)d_in[1];
    // d_in[2] = batch_size scalar (fixed at 4; dims are compile-time constants)

    float* out  = (float*)d_out;
    int*   map  = (int*)d_ws;                      // 4 MB: B*NX*NY int32
    const int MAPN = BC * NXC * NYC;               // 1,048,576
    float* zrow = (float*)(map + MAPN);            // 256 B zero row after map

    const int N = in_sizes[0] / CC;                // 120000 pillars

    // Zero map + zero-row via async memset (graph-capture-legal; the harness
    // itself uses hipMemsetAsync). Saves one kernel launch vs a zero kernel.
    hipMemsetAsync(map, 0, (size_t)MAPN * sizeof(int) + CC * sizeof(float), stream);

    pp_build_map<<<(N + 255) / 256, 256, 0, stream>>>(coords, map, N);
    pp_gather<<<BC * NXC, 256, 0, stream>>>(vf, map, zrow, out);
}